// Round 6
// baseline (141.943 us; speedup 1.0000x reference)
//
#include <hip/hip_runtime.h>
#include <hip/hip_bf16.h>

#define BB 2
#define SS 2048
#define HH 16
#define DD 64

#define LOG2E 1.4426950408889634f

typedef __bf16 bf16x8 __attribute__((ext_vector_type(8)));
typedef __bf16 bf16x4 __attribute__((ext_vector_type(4)));
typedef float f32x4 __attribute__((ext_vector_type(4)));

__device__ __forceinline__ void gld16(const __hip_bfloat16* g, __hip_bfloat16* l) {
    __builtin_amdgcn_global_load_lds(
        (const __attribute__((address_space(1))) unsigned int*)g,
        (__attribute__((address_space(3))) unsigned int*)l, 16, 0, 0);
}

// ---------------------------------------------------------------------------
// Kernel 1: fused Q/K/V projection + V transpose + Q pre-scaling.
//   Q, K  -> [B,H,S,D] bf16 (Q pre-multiplied by log2e/inv_scale)
//   V     -> Vt [B,H,D,S] bf16 (transposed)
// ---------------------------------------------------------------------------
__global__ __launch_bounds__(256) void proj_kernel(
    const float* __restrict__ xq, const float* __restrict__ xk,
    const float* __restrict__ xv,
    const float* __restrict__ Wq, const float* __restrict__ bq,
    const float* __restrict__ Wk, const float* __restrict__ bk,
    const float* __restrict__ Wv, const float* __restrict__ bv,
    const float* __restrict__ inv_scale_p,
    __hip_bfloat16* __restrict__ Qp, __hip_bfloat16* __restrict__ Kp,
    __hip_bfloat16* __restrict__ Vt)
{
    __shared__ float w_lds[64][65];                                  // [d][e]
    __shared__ __attribute__((aligned(16))) float x_lds[64][72];     // [row][d]
    __shared__ __attribute__((aligned(16))) __hip_bfloat16 vt_lds[64][72]; // [e][row]

    const int tid = threadIdx.x;
    const int bh = blockIdx.x;
    const int b = bh >> 4, h = bh & 15;
    const int s0 = blockIdx.y * 64;
    const int e = tid & 63;
    const int rg = tid >> 6;
    const float qscale = LOG2E / inv_scale_p[0];

    const float* xs[3] = {xq, xk, xv};
    const float* Ws[3] = {Wq, Wk, Wv};
    const float* Bs[3] = {bq, bk, bv};

#pragma unroll
    for (int m = 0; m < 3; ++m) {
        __syncthreads();
#pragma unroll
        for (int k = 0; k < 16; ++k) {
            const int i = tid + k * 256;
            w_lds[i & 63][i >> 6] = Ws[m][i];
        }
        {
            const int row = tid >> 2, f0 = tid & 3;
            const float* xrow = xs[m] + ((size_t)((b * SS + s0 + row) * HH + h)) * DD;
            float4* dst = (float4*)&x_lds[row][0];
            const float4* src = (const float4*)xrow;
#pragma unroll
            for (int j = 0; j < 4; ++j) dst[f0 + 4 * j] = src[f0 + 4 * j];
        }
        const float bias_e = Bs[m][e];
        __syncthreads();

        float acc[16];
#pragma unroll
        for (int it = 0; it < 16; ++it) acc[it] = bias_e;
#pragma unroll
        for (int dq = 0; dq < 16; ++dq) {
            const float w0 = w_lds[dq * 4 + 0][e];
            const float w1 = w_lds[dq * 4 + 1][e];
            const float w2 = w_lds[dq * 4 + 2][e];
            const float w3 = w_lds[dq * 4 + 3][e];
#pragma unroll
            for (int it = 0; it < 16; ++it) {
                const float4 x4 = *(const float4*)&x_lds[rg * 16 + it][dq * 4];
                acc[it] = fmaf(x4.x, w0, fmaf(x4.y, w1, fmaf(x4.z, w2, fmaf(x4.w, w3, acc[it]))));
            }
        }

        if (m == 0) {
#pragma unroll
            for (int it = 0; it < 16; ++it)
                Qp[((size_t)bh * SS + s0 + rg * 16 + it) * DD + e] =
                    __float2bfloat16(acc[it] * qscale);
        } else if (m == 1) {
#pragma unroll
            for (int it = 0; it < 16; ++it)
                Kp[((size_t)bh * SS + s0 + rg * 16 + it) * DD + e] =
                    __float2bfloat16(acc[it]);
        } else {
#pragma unroll
            for (int it = 0; it < 16; ++it)
                vt_lds[e][rg * 16 + it] = __float2bfloat16(acc[it]);
            __syncthreads();
            const int row2 = tid >> 2, f = tid & 3;
            bf16x8 vv0 = *(const bf16x8*)&vt_lds[row2][f * 16];
            bf16x8 vv1 = *(const bf16x8*)&vt_lds[row2][f * 16 + 8];
            __hip_bfloat16* dst = &Vt[((size_t)bh * DD + row2) * SS + s0 + f * 16];
            *(bf16x8*)dst = vv0;
            *(bf16x8*)(dst + 8) = vv1;
        }
    }
}

// ---------------------------------------------------------------------------
// Kernel 2: flash attention.  LDS-staged K/V (dbuf, XOR-swz), swapped QK^T,
// defer-max online softmax (no shuffles on common path), reg-dbuf mask
// prefetch, permuted-k PV.  All in exp2 domain (Q pre-scaled by log2e).
// grid = (B*H, S/64); block = 256 (4 waves); 1 barrier per t-tile.
// ---------------------------------------------------------------------------
__global__ __launch_bounds__(256, 4) void attn_kernel(
    const __hip_bfloat16* __restrict__ Qp, const __hip_bfloat16* __restrict__ Kp,
    const __hip_bfloat16* __restrict__ Vt, const float* __restrict__ mask,
    float* __restrict__ out)
{
    __shared__ __attribute__((aligned(16))) __hip_bfloat16 Kl[2][4096];
    __shared__ __attribute__((aligned(16))) __hip_bfloat16 Vl[2][4096];

    const int tid = threadIdx.x;
    const int lane = tid & 63;
    const int wave = tid >> 6;
    const int lm = lane & 15;
    const int lg = lane >> 4;
    const int bh = blockIdx.x;
    const int qt = blockIdx.y;
    const int b = bh >> 4;

    const __hip_bfloat16* Qb = Qp + (size_t)bh * SS * DD;
    const __hip_bfloat16* Kb = Kp + (size_t)bh * SS * DD;
    const __hip_bfloat16* Vtb = Vt + (size_t)bh * DD * SS;

    const int q0 = qt * 64 + wave * 16;
    const float* mq = mask + (size_t)b * SS * SS + (size_t)(q0 + lm) * SS;

    const int srow = lane >> 3;
    const int scol = ((lane & 7) ^ srow) * 8;
    const int swz = (lm & 7) << 4;

    bf16x8 qf[2];
    {
        const __hip_bfloat16* qptr = Qb + (size_t)(q0 + lm) * DD + lg * 8;
        qf[0] = *reinterpret_cast<const bf16x8*>(qptr);
        qf[1] = *reinterpret_cast<const bf16x8*>(qptr + 32);
    }

    f32x4 o[4];
    float m_r = -1e30f;     // running max (log2 domain), per q = q0+lm
    float l_p = 0.f;        // LANE-LOCAL partial denominator (this lane's t's)
#pragma unroll
    for (int i = 0; i < 4; ++i) o[i] = f32x4{0.f, 0.f, 0.f, 0.f};

#define STAGE(bufi, t0s)                                                        \
    {                                                                           \
        _Pragma("unroll")                                                       \
        for (int cc = 0; cc < 2; ++cc) {                                        \
            const int c = wave * 2 + cc;                                        \
            const int row = c * 8 + srow;                                       \
            gld16(Kb + (size_t)((t0s) + row) * DD + scol, &Kl[bufi][c * 512]);  \
            gld16(Vtb + (size_t)row * SS + (t0s) + scol, &Vl[bufi][c * 512]);   \
        }                                                                       \
    }

#define KFRAG(nt, kc) (*(const bf16x8*)((const char*)Kl[buf] +                  \
        (((nt) * 16 + lm) << 7) + ((((kc) * 64) + lg * 16) ^ swz)))
#define VLO(dn, kc) (*(const bf16x4*)((const char*)Vl[buf] +                    \
        (((dn) * 16 + lm) << 7) + ((((kc) * 64) + lg * 8) ^ swz)))
#define VHI(dn, kc) (*(const bf16x4*)((const char*)Vl[buf] +                    \
        (((dn) * 16 + lm) << 7) + ((((kc) * 64 + 32) + lg * 8) ^ swz)))

    // prologue: stage tile 0 + prefetch mask tile 0
    STAGE(0, 0);
    f32x4 mv[4];
#pragma unroll
    for (int nt = 0; nt < 4; ++nt)
        mv[nt] = *(const f32x4*)&mq[nt * 16 + lg * 4];
    __syncthreads();

    int buf = 0;
    for (int t0 = 0; t0 < SS; t0 += 64) {
        // ---- prefetch NEXT tile's mask (consumed next iteration) ----
        f32x4 mv_nxt[4];
        if (t0 + 64 < SS) {
#pragma unroll
            for (int nt = 0; nt < 4; ++nt)
                mv_nxt[nt] = *(const f32x4*)&mq[t0 + 64 + nt * 16 + lg * 4];
        }
        if (t0 + 64 < SS) STAGE(buf ^ 1, t0 + 64);

        // ---- QK^T (swapped): col=q(lm), row=t(16nt+4lg+r); log2 domain ----
        f32x4 s[4];
#pragma unroll
        for (int nt = 0; nt < 4; ++nt) s[nt] = f32x4{0.f, 0.f, 0.f, 0.f};
#pragma unroll
        for (int kc = 0; kc < 2; ++kc) {
            bf16x8 k0 = KFRAG(0, kc), k1 = KFRAG(1, kc);
            bf16x8 k2 = KFRAG(2, kc), k3 = KFRAG(3, kc);
            s[0] = __builtin_amdgcn_mfma_f32_16x16x32_bf16(k0, qf[kc], s[0], 0, 0, 0);
            s[1] = __builtin_amdgcn_mfma_f32_16x16x32_bf16(k1, qf[kc], s[1], 0, 0, 0);
            s[2] = __builtin_amdgcn_mfma_f32_16x16x32_bf16(k2, qf[kc], s[2], 0, 0, 0);
            s[3] = __builtin_amdgcn_mfma_f32_16x16x32_bf16(k3, qf[kc], s[3], 0, 0, 0);
        }

        // ---- mask fma (mask * log2e + s) ----
        float sv[4][4];
#pragma unroll
        for (int nt = 0; nt < 4; ++nt)
#pragma unroll
            for (int r = 0; r < 4; ++r)
                sv[nt][r] = fmaf(mv[nt][r], LOG2E, s[nt][r]);

        // ---- defer-max: lane-local max via max3 tree + wave vote ----
        float pmax = fmaxf(fmaxf(fmaxf(sv[0][0], sv[0][1]), sv[0][2]), sv[0][3]);
        pmax = fmaxf(pmax, fmaxf(fmaxf(sv[1][0], sv[1][1]), fmaxf(sv[1][2], sv[1][3])));
        pmax = fmaxf(pmax, fmaxf(fmaxf(sv[2][0], sv[2][1]), fmaxf(sv[2][2], sv[2][3])));
        pmax = fmaxf(pmax, fmaxf(fmaxf(sv[3][0], sv[3][1]), fmaxf(sv[3][2], sv[3][3])));

        if (!__all(pmax - m_r <= 11.5f)) {
            // slow path (rare): full row-max reduce + rescale state
            float mx = pmax;
            mx = fmaxf(mx, __shfl_xor(mx, 16));
            mx = fmaxf(mx, __shfl_xor(mx, 32));
            const float mn = fmaxf(m_r, mx);
            const float alpha = exp2f(m_r - mn);   // per q=lm, lg-consistent
            m_r = mn;
            l_p *= alpha;
#pragma unroll
            for (int r = 0; r < 4; ++r) {
                const float a = __shfl(alpha, lg * 4 + r);
                o[0][r] *= a; o[1][r] *= a; o[2][r] *= a; o[3][r] *= a;
            }
        }

        // ---- P = exp2(sv - m); lane-local l accumulation; pack in place ----
        float pv[4][4];
#pragma unroll
        for (int nt = 0; nt < 4; ++nt)
#pragma unroll
            for (int r = 0; r < 4; ++r) {
                const float p = exp2f(sv[nt][r] - m_r);
                pv[nt][r] = p;
                l_p += p;
            }

        bf16x8 pfa[2];
#pragma unroll
        for (int kc = 0; kc < 2; ++kc) {
            bf16x8 pf;
            pf[0] = (__bf16)pv[2 * kc][0];     pf[1] = (__bf16)pv[2 * kc][1];
            pf[2] = (__bf16)pv[2 * kc][2];     pf[3] = (__bf16)pv[2 * kc][3];
            pf[4] = (__bf16)pv[2 * kc + 1][0]; pf[5] = (__bf16)pv[2 * kc + 1][1];
            pf[6] = (__bf16)pv[2 * kc + 1][2]; pf[7] = (__bf16)pv[2 * kc + 1][3];
            pfa[kc] = pf;
        }

        // ---- O += P @ V (permuted-k fragments) ----
#pragma unroll
        for (int kc = 0; kc < 2; ++kc)
#pragma unroll
            for (int dn = 0; dn < 4; ++dn) {
                bf16x4 lo = VLO(dn, kc), hi = VHI(dn, kc);
                bf16x8 vf;
                vf[0] = lo[0]; vf[1] = lo[1]; vf[2] = lo[2]; vf[3] = lo[3];
                vf[4] = hi[0]; vf[5] = hi[1]; vf[6] = hi[2]; vf[7] = hi[3];
                o[dn] = __builtin_amdgcn_mfma_f32_16x16x32_bf16(pfa[kc], vf, o[dn], 0, 0, 0);
            }

        // rotate mask buffer
#pragma unroll
        for (int nt = 0; nt < 4; ++nt) mv[nt] = mv_nxt[nt];

        __syncthreads();
        buf ^= 1;
    }

    // ---- epilogue: one-time l reduce + broadcast, normalize, store ----
    float lt = l_p;
    lt += __shfl_xor(lt, 16);
    lt += __shfl_xor(lt, 32);
    float lv[4];
#pragma unroll
    for (int r = 0; r < 4; ++r) lv[r] = __shfl(lt, lg * 4 + r);
#pragma unroll
    for (int dn = 0; dn < 4; ++dn)
#pragma unroll
        for (int r = 0; r < 4; ++r) {
            const int q = q0 + lg * 4 + r;
            out[((size_t)bh * SS + q) * DD + dn * 16 + lm] = o[dn][r] / lv[r];
        }
#undef STAGE
#undef KFRAG
#undef VLO
#undef VHI
}

extern "C" void kernel_launch(void* const* d_in, const int* in_sizes, int n_in,
                              void* d_out, int out_size, void* d_ws, size_t ws_size,
                              hipStream_t stream) {
    const float* xq        = (const float*)d_in[0];
    const float* xk        = (const float*)d_in[1];
    const float* xv        = (const float*)d_in[2];
    const float* mask      = (const float*)d_in[3];
    const float* inv_scale = (const float*)d_in[4];
    const float* Wq        = (const float*)d_in[5];
    const float* bq        = (const float*)d_in[6];
    const float* Wk        = (const float*)d_in[7];
    const float* bk        = (const float*)d_in[8];
    const float* Wv        = (const float*)d_in[9];
    const float* bv        = (const float*)d_in[10];

    __hip_bfloat16* Qp = (__hip_bfloat16*)d_ws;
    __hip_bfloat16* Kp = Qp + (size_t)BB * HH * SS * DD;
    __hip_bfloat16* Vt = Kp + (size_t)BB * HH * SS * DD;
    float* out = (float*)d_out;

    proj_kernel<<<dim3(BB * HH, SS / 64), dim3(256), 0, stream>>>(
        xq, xk, xv, Wq, bq, Wk, bk, Wv, bv, inv_scale, Qp, Kp, Vt);

    attn_kernel<<<dim3(BB * HH, SS / 64), dim3(256), 0, stream>>>(
        Qp, Kp, Vt, mask, out);
}

// Round 7
// 129.669 us; speedup vs baseline: 1.0947x; 1.0947x over previous
//
#include <hip/hip_runtime.h>
#include <hip/hip_bf16.h>

#define BB 2
#define SS 2048
#define HH 16
#define DD 64

#define LOG2E 1.4426950408889634f

typedef __bf16 bf16x8 __attribute__((ext_vector_type(8)));
typedef __bf16 bf16x4 __attribute__((ext_vector_type(4)));
typedef float f32x4 __attribute__((ext_vector_type(4)));

__device__ __forceinline__ void gld16(const __hip_bfloat16* g, __hip_bfloat16* l) {
    __builtin_amdgcn_global_load_lds(
        (const __attribute__((address_space(1))) unsigned int*)g,
        (__attribute__((address_space(3))) unsigned int*)l, 16, 0, 0);
}

// ---------------------------------------------------------------------------
// Kernel 1: fused Q/K/V projection + V transpose + Q pre-scaling.
//   Q, K  -> [B,H,S,D] bf16 (Q pre-multiplied by log2e/inv_scale)
//   V     -> Vt [B,H,D,S] bf16 (transposed)
// ---------------------------------------------------------------------------
__global__ __launch_bounds__(256) void proj_kernel(
    const float* __restrict__ xq, const float* __restrict__ xk,
    const float* __restrict__ xv,
    const float* __restrict__ Wq, const float* __restrict__ bq,
    const float* __restrict__ Wk, const float* __restrict__ bk,
    const float* __restrict__ Wv, const float* __restrict__ bv,
    const float* __restrict__ inv_scale_p,
    __hip_bfloat16* __restrict__ Qp, __hip_bfloat16* __restrict__ Kp,
    __hip_bfloat16* __restrict__ Vt)
{
    __shared__ float w_lds[64][65];                                  // [d][e]
    __shared__ __attribute__((aligned(16))) float x_lds[64][72];     // [row][d]
    __shared__ __attribute__((aligned(16))) __hip_bfloat16 vt_lds[64][72]; // [e][row]

    const int tid = threadIdx.x;
    const int bh = blockIdx.x;
    const int b = bh >> 4, h = bh & 15;
    const int s0 = blockIdx.y * 64;
    const int e = tid & 63;
    const int rg = tid >> 6;
    const float qscale = LOG2E / inv_scale_p[0];

    const float* xs[3] = {xq, xk, xv};
    const float* Ws[3] = {Wq, Wk, Wv};
    const float* Bs[3] = {bq, bk, bv};

#pragma unroll
    for (int m = 0; m < 3; ++m) {
        __syncthreads();
#pragma unroll
        for (int k = 0; k < 16; ++k) {
            const int i = tid + k * 256;
            w_lds[i & 63][i >> 6] = Ws[m][i];
        }
        {
            const int row = tid >> 2, f0 = tid & 3;
            const float* xrow = xs[m] + ((size_t)((b * SS + s0 + row) * HH + h)) * DD;
            float4* dst = (float4*)&x_lds[row][0];
            const float4* src = (const float4*)xrow;
#pragma unroll
            for (int j = 0; j < 4; ++j) dst[f0 + 4 * j] = src[f0 + 4 * j];
        }
        const float bias_e = Bs[m][e];
        __syncthreads();

        float acc[16];
#pragma unroll
        for (int it = 0; it < 16; ++it) acc[it] = bias_e;
#pragma unroll
        for (int dq = 0; dq < 16; ++dq) {
            const float w0 = w_lds[dq * 4 + 0][e];
            const float w1 = w_lds[dq * 4 + 1][e];
            const float w2 = w_lds[dq * 4 + 2][e];
            const float w3 = w_lds[dq * 4 + 3][e];
#pragma unroll
            for (int it = 0; it < 16; ++it) {
                const float4 x4 = *(const float4*)&x_lds[rg * 16 + it][dq * 4];
                acc[it] = fmaf(x4.x, w0, fmaf(x4.y, w1, fmaf(x4.z, w2, fmaf(x4.w, w3, acc[it]))));
            }
        }

        if (m == 0) {
#pragma unroll
            for (int it = 0; it < 16; ++it)
                Qp[((size_t)bh * SS + s0 + rg * 16 + it) * DD + e] =
                    __float2bfloat16(acc[it] * qscale);
        } else if (m == 1) {
#pragma unroll
            for (int it = 0; it < 16; ++it)
                Kp[((size_t)bh * SS + s0 + rg * 16 + it) * DD + e] =
                    __float2bfloat16(acc[it]);
        } else {
#pragma unroll
            for (int it = 0; it < 16; ++it)
                vt_lds[e][rg * 16 + it] = __float2bfloat16(acc[it]);
            __syncthreads();
            const int row2 = tid >> 2, f = tid & 3;
            bf16x8 vv0 = *(const bf16x8*)&vt_lds[row2][f * 16];
            bf16x8 vv1 = *(const bf16x8*)&vt_lds[row2][f * 16 + 8];
            __hip_bfloat16* dst = &Vt[((size_t)bh * DD + row2) * SS + s0 + f * 16];
            *(bf16x8*)dst = vv0;
            *(bf16x8*)(dst + 8) = vv1;
        }
    }
}

// ---------------------------------------------------------------------------
// Kernel 2: flash attention.  LDS-staged K/V (dbuf, XOR-swz), swapped QK^T,
// defer-max online softmax, l accumulated via ones-column MFMA (no shuffles
// anywhere on the common path or epilogue), permuted-k PV.
// grid = (B*H, S/64); block = 256 (4 waves); 1 barrier per t-tile.
// ---------------------------------------------------------------------------
__global__ __launch_bounds__(256, 4) void attn_kernel(
    const __hip_bfloat16* __restrict__ Qp, const __hip_bfloat16* __restrict__ Kp,
    const __hip_bfloat16* __restrict__ Vt, const float* __restrict__ mask,
    float* __restrict__ out)
{
    __shared__ __attribute__((aligned(16))) __hip_bfloat16 Kl[2][4096];
    __shared__ __attribute__((aligned(16))) __hip_bfloat16 Vl[2][4096];

    const int tid = threadIdx.x;
    const int lane = tid & 63;
    const int wave = tid >> 6;
    const int lm = lane & 15;
    const int lg = lane >> 4;
    const int bh = blockIdx.x;
    const int qt = blockIdx.y;
    const int b = bh >> 4;

    const __hip_bfloat16* Qb = Qp + (size_t)bh * SS * DD;
    const __hip_bfloat16* Kb = Kp + (size_t)bh * SS * DD;
    const __hip_bfloat16* Vtb = Vt + (size_t)bh * DD * SS;

    const int q0 = qt * 64 + wave * 16;
    const float* mq = mask + (size_t)b * SS * SS + (size_t)(q0 + lm) * SS;

    const int srow = lane >> 3;
    const int scol = ((lane & 7) ^ srow) * 8;
    const int swz = (lm & 7) << 4;

    bf16x8 qf[2];
    {
        const __hip_bfloat16* qptr = Qb + (size_t)(q0 + lm) * DD + lg * 8;
        qf[0] = *reinterpret_cast<const bf16x8*>(qptr);
        qf[1] = *reinterpret_cast<const bf16x8*>(qptr + 32);
    }

    bf16x8 ones;
#pragma unroll
    for (int i = 0; i < 8; ++i) ones[i] = (__bf16)1.0f;

    f32x4 o[4];
    f32x4 lacc = f32x4{0.f, 0.f, 0.f, 0.f};   // denominator, same row-layout as o
    float m_r = -1e30f;                        // running max (log2 domain), q = q0+lm
#pragma unroll
    for (int i = 0; i < 4; ++i) o[i] = f32x4{0.f, 0.f, 0.f, 0.f};

#define STAGE(bufi, t0s)                                                        \
    {                                                                           \
        _Pragma("unroll")                                                       \
        for (int cc = 0; cc < 2; ++cc) {                                        \
            const int c = wave * 2 + cc;                                        \
            const int row = c * 8 + srow;                                       \
            gld16(Kb + (size_t)((t0s) + row) * DD + scol, &Kl[bufi][c * 512]);  \
            gld16(Vtb + (size_t)row * SS + (t0s) + scol, &Vl[bufi][c * 512]);   \
        }                                                                       \
    }

#define KFRAG(nt, kc) (*(const bf16x8*)((const char*)Kl[buf] +                  \
        (((nt) * 16 + lm) << 7) + ((((kc) * 64) + lg * 16) ^ swz)))
#define VLO(dn, kc) (*(const bf16x4*)((const char*)Vl[buf] +                    \
        (((dn) * 16 + lm) << 7) + ((((kc) * 64) + lg * 8) ^ swz)))
#define VHI(dn, kc) (*(const bf16x4*)((const char*)Vl[buf] +                    \
        (((dn) * 16 + lm) << 7) + ((((kc) * 64 + 32) + lg * 8) ^ swz)))

    // prologue: stage tile 0
    STAGE(0, 0);
    __syncthreads();

    int buf = 0;
    for (int t0 = 0; t0 < SS; t0 += 64) {
        const bool has_next = (t0 + 64 < SS);
        if (has_next) STAGE(buf ^ 1, t0 + 64);

        // ---- mask load for this tile (consumed after QK^T) ----
        f32x4 mv[4];
#pragma unroll
        for (int nt = 0; nt < 4; ++nt)
            mv[nt] = *(const f32x4*)&mq[t0 + nt * 16 + lg * 4];

        // ---- QK^T (swapped): col=q(lm), row=t(16nt+4lg+r); log2 domain ----
        f32x4 s[4];
#pragma unroll
        for (int nt = 0; nt < 4; ++nt) s[nt] = f32x4{0.f, 0.f, 0.f, 0.f};
#pragma unroll
        for (int kc = 0; kc < 2; ++kc) {
            bf16x8 k0 = KFRAG(0, kc), k1 = KFRAG(1, kc);
            bf16x8 k2 = KFRAG(2, kc), k3 = KFRAG(3, kc);
            s[0] = __builtin_amdgcn_mfma_f32_16x16x32_bf16(k0, qf[kc], s[0], 0, 0, 0);
            s[1] = __builtin_amdgcn_mfma_f32_16x16x32_bf16(k1, qf[kc], s[1], 0, 0, 0);
            s[2] = __builtin_amdgcn_mfma_f32_16x16x32_bf16(k2, qf[kc], s[2], 0, 0, 0);
            s[3] = __builtin_amdgcn_mfma_f32_16x16x32_bf16(k3, qf[kc], s[3], 0, 0, 0);
        }

        // ---- V fragments: issue DS reads now, hide latency under softmax ----
        bf16x8 vfr[8];
#pragma unroll
        for (int kc = 0; kc < 2; ++kc)
#pragma unroll
            for (int dn = 0; dn < 4; ++dn) {
                bf16x4 lo = VLO(dn, kc), hi = VHI(dn, kc);
                bf16x8 vf;
                vf[0] = lo[0]; vf[1] = lo[1]; vf[2] = lo[2]; vf[3] = lo[3];
                vf[4] = hi[0]; vf[5] = hi[1]; vf[6] = hi[2]; vf[7] = hi[3];
                vfr[kc * 4 + dn] = vf;
            }

        // ---- mask fma (log2 domain) ----
        float sv[4][4];
#pragma unroll
        for (int nt = 0; nt < 4; ++nt)
#pragma unroll
            for (int r = 0; r < 4; ++r)
                sv[nt][r] = fmaf(mv[nt][r], LOG2E, s[nt][r]);

        // ---- defer-max: lane-local max via max3-fusable tree + wave vote ----
        float a0 = fmaxf(sv[0][0], fmaxf(sv[0][1], sv[0][2]));
        float a1 = fmaxf(sv[0][3], fmaxf(sv[1][0], sv[1][1]));
        float a2 = fmaxf(sv[1][2], fmaxf(sv[1][3], sv[2][0]));
        float a3 = fmaxf(sv[2][1], fmaxf(sv[2][2], sv[2][3]));
        float a4 = fmaxf(sv[3][0], fmaxf(sv[3][1], sv[3][2]));
        float pmax = fmaxf(sv[3][3], fmaxf(a0, a1));
        pmax = fmaxf(pmax, fmaxf(a2, fmaxf(a3, a4)));

        if (!__all(pmax - m_r <= 11.5f)) {
            // slow path (rare): full row-max reduce + rescale state
            float mx = pmax;
            mx = fmaxf(mx, __shfl_xor(mx, 16));
            mx = fmaxf(mx, __shfl_xor(mx, 32));
            const float mn = fmaxf(m_r, mx);
            const float alpha = exp2f(m_r - mn);
            m_r = mn;
#pragma unroll
            for (int r = 0; r < 4; ++r) {
                const float a = __shfl(alpha, lg * 4 + r);
                o[0][r] *= a; o[1][r] *= a; o[2][r] *= a; o[3][r] *= a;
                lacc[r] *= a;
            }
        }

        // ---- P = exp2(sv - m) in place; pack to bf16 fragments ----
#pragma unroll
        for (int nt = 0; nt < 4; ++nt)
#pragma unroll
            for (int r = 0; r < 4; ++r)
                sv[nt][r] = exp2f(sv[nt][r] - m_r);

        bf16x8 pfa[2];
#pragma unroll
        for (int kc = 0; kc < 2; ++kc) {
            bf16x8 pf;
            pf[0] = (__bf16)sv[2 * kc][0];     pf[1] = (__bf16)sv[2 * kc][1];
            pf[2] = (__bf16)sv[2 * kc][2];     pf[3] = (__bf16)sv[2 * kc][3];
            pf[4] = (__bf16)sv[2 * kc + 1][0]; pf[5] = (__bf16)sv[2 * kc + 1][1];
            pf[6] = (__bf16)sv[2 * kc + 1][2]; pf[7] = (__bf16)sv[2 * kc + 1][3];
            pfa[kc] = pf;
        }

        // ---- O += P @ V ; l += P @ ones (same MFMA row layout as o) ----
#pragma unroll
        for (int kc = 0; kc < 2; ++kc) {
            lacc = __builtin_amdgcn_mfma_f32_16x16x32_bf16(pfa[kc], ones, lacc, 0, 0, 0);
#pragma unroll
            for (int dn = 0; dn < 4; ++dn)
                o[dn] = __builtin_amdgcn_mfma_f32_16x16x32_bf16(pfa[kc], vfr[kc * 4 + dn], o[dn], 0, 0, 0);
        }

        __syncthreads();
        buf ^= 1;
    }

    // ---- epilogue: normalize (l already in o-row layout) and store ----
#pragma unroll
    for (int r = 0; r < 4; ++r) {
        const float inv_l = 1.0f / lacc[r];
        const int q = q0 + lg * 4 + r;
#pragma unroll
        for (int dn = 0; dn < 4; ++dn)
            out[((size_t)bh * SS + q) * DD + dn * 16 + lm] = o[dn][r] * inv_l;
    }
#undef STAGE
#undef KFRAG
#undef VLO
#undef VHI
}

extern "C" void kernel_launch(void* const* d_in, const int* in_sizes, int n_in,
                              void* d_out, int out_size, void* d_ws, size_t ws_size,
                              hipStream_t stream) {
    const float* xq        = (const float*)d_in[0];
    const float* xk        = (const float*)d_in[1];
    const float* xv        = (const float*)d_in[2];
    const float* mask      = (const float*)d_in[3];
    const float* inv_scale = (const float*)d_in[4];
    const float* Wq        = (const float*)d_in[5];
    const float* bq        = (const float*)d_in[6];
    const float* Wk        = (const float*)d_in[7];
    const float* bk        = (const float*)d_in[8];
    const float* Wv        = (const float*)d_in[9];
    const float* bv        = (const float*)d_in[10];

    __hip_bfloat16* Qp = (__hip_bfloat16*)d_ws;
    __hip_bfloat16* Kp = Qp + (size_t)BB * HH * SS * DD;
    __hip_bfloat16* Vt = Kp + (size_t)BB * HH * SS * DD;
    float* out = (float*)d_out;

    proj_kernel<<<dim3(BB * HH, SS / 64), dim3(256), 0, stream>>>(
        xq, xk, xv, Wq, bq, Wk, bk, Wv, bv, inv_scale, Qp, Kp, Vt);

    attn_kernel<<<dim3(BB * HH, SS / 64), dim3(256), 0, stream>>>(
        Qp, Kp, Vt, mask, out);
}